// Round 7
// baseline (278.806 us; speedup 1.0000x reference)
//
#include <hip/hip_runtime.h>
#include <math.h>

#define B_ROWS 4096
#define D_DIM  1024
static constexpr float TEMP = 0.2f;
static constexpr float FP8_SCALE = 16.0f;        // per-side scale before cast
static constexpr float INV_S2 = 1.0f / 256.0f;   // 1/SCALE^2: acc -> sim

typedef __attribute__((ext_vector_type(8))) int    i32x8;
typedef __attribute__((ext_vector_type(16))) float f32x16;

// float -> OCP e4m3fn byte, RNE. Data path: |f| <= ~4, no NaN/inf.
__device__ inline unsigned char f2fp8(float f) {
    unsigned int u = __float_as_uint(f);
    unsigned int s = (u >> 24) & 0x80u;
    float af = fabsf(f);
    unsigned char b;
    if (af >= 0x1.0p-6f) {                 // normal e4m3 range
        unsigned int au = u & 0x7fffffffu;
        unsigned int lsb = (au >> 20) & 1u;
        au += 0x7ffffu + lsb;              // RNE into 3 mantissa bits
        int e = (int)(au >> 23) - 127 + 7;
        unsigned int m = (au >> 20) & 7u;
        if (e > 15 || (e == 15 && m > 6)) b = 0x7e;   // saturate 448
        else b = (unsigned char)((e << 3) | m);
    } else {                               // subnormal: quantum 2^-9
        int q = (int)rintf(af * 512.0f);
        b = (unsigned char)(q >= 8 ? 0x08 : q);
    }
    return (unsigned char)(b | s);
}

__device__ inline unsigned int f2fp8x4(float4 v) {
    return (unsigned int)f2fp8(v.x)
         | ((unsigned int)f2fp8(v.y) << 8)
         | ((unsigned int)f2fp8(v.z) << 16)
         | ((unsigned int)f2fp8(v.w) << 24);
}

// async global->LDS, 16 B/lane; LDS dest = wave-uniform base + lane*16
__device__ inline void gload_lds16(const unsigned char* g, unsigned char* l) {
    __builtin_amdgcn_global_load_lds(
        (const __attribute__((address_space(1))) unsigned int*)g,
        (__attribute__((address_space(3))) unsigned int*)l,
        16, 0, 0);
}

// two ds_read_b128 -> one 8-VGPR fragment (regs 0..3 = lower 16 k-bytes)
__device__ inline i32x8 ld_frag(const unsigned char* row, int o0, int o1) {
    union { i32x8 v; int4 q[2]; } u;
    u.q[0] = *(const int4*)(row + o0);
    u.q[1] = *(const int4*)(row + o1);
    return u.v;
}

// ws layout: w[0]=pos acc, w[1]=neg acc, w[2]=finalize ticket (u32),
//            then Zi8 (4096x1024 fp8) at byte (w+16), Zj8 after.

// Wave-per-row normalize (fp32) + scale by 16 + cast to fp8 e4m3.
__global__ __launch_bounds__(256) void norm_cast_kernel(
        const float* __restrict__ emb_i, const float* __restrict__ emb_j,
        unsigned char* __restrict__ Zi8, unsigned char* __restrict__ Zj8,
        float* __restrict__ w) {
    const int tid = threadIdx.x;
    if (blockIdx.x == 0 && tid == 0) {
        w[0] = 0.0f; w[1] = 0.0f;
        ((unsigned int*)w)[2] = 0u;
    }
    const int wave = tid >> 6, lane = tid & 63;
    const int row = blockIdx.x * 4 + wave;          // 0..8191
    const float* src; unsigned char* dst; int r;
    if (row < B_ROWS) { src = emb_i; dst = Zi8; r = row; }
    else              { src = emb_j; dst = Zj8; r = row - B_ROWS; }

    const float4* p = (const float4*)(src + (size_t)r * D_DIM);
    float4 v0 = p[lane], v1 = p[64 + lane], v2 = p[128 + lane], v3 = p[192 + lane];
    float s = v0.x*v0.x + v0.y*v0.y + v0.z*v0.z + v0.w*v0.w
            + v1.x*v1.x + v1.y*v1.y + v1.z*v1.z + v1.w*v1.w
            + v2.x*v2.x + v2.y*v2.y + v2.z*v2.z + v2.w*v2.w
            + v3.x*v3.x + v3.y*v3.y + v3.z*v3.z + v3.w*v3.w;
    #pragma unroll
    for (int m = 1; m < 64; m <<= 1) s += __shfl_xor(s, m, 64);
    const float inv = FP8_SCALE / fmaxf(sqrtf(s), 1e-12f);

    float4 a0 = {v0.x*inv, v0.y*inv, v0.z*inv, v0.w*inv};
    float4 a1 = {v1.x*inv, v1.y*inv, v1.z*inv, v1.w*inv};
    float4 a2 = {v2.x*inv, v2.y*inv, v2.z*inv, v2.w*inv};
    float4 a3 = {v3.x*inv, v3.y*inv, v3.z*inv, v3.w*inv};
    unsigned int* q = (unsigned int*)(dst + (size_t)r * D_DIM);
    q[lane]       = f2fp8x4(a0);
    q[64 + lane]  = f2fp8x4(a1);
    q[128 + lane] = f2fp8x4(a2);
    q[192 + lane] = f2fp8x4(a3);
}

// 128x256 block tile, BK=128, 4 waves in 2x2; wave owns 64x128 = 2x4 tiles
// of 32x32, computed with mfma_scale_f32_32x32x64_f8f6f4 (unit e8m0 scales
// = pure fp8 matmul at 2x the non-scaled rate). Grid 16x32 = 512 = 2/CU.
//
// LDS row = 128 B = 8 x 16B pieces, XOR swizzle p = (c + row&7) & 7.
// Staging (global_load_lds, lane*16 dest) fetches the swizzled *global*
// piece. Fragment reads are 2x ds_read_b128 per (tile, k-block): in every
// 16-lane phase each bank is hit exactly 2x at 16B granularity -> same
// structure R4 measured at zero conflicts.
__global__ __launch_bounds__(256, 2) void simloss_mxfp8_kernel(
        const unsigned char* __restrict__ Zi8,
        const unsigned char* __restrict__ Zj8,
        float* __restrict__ w, float* __restrict__ out) {
    __shared__ __align__(16) unsigned char lA[128 * 128];  // 16 KB (Zj rows)
    __shared__ __align__(16) unsigned char lB[256 * 128];  // 32 KB (Zi rows)
    __shared__ float rn[4], rp[4];

    const int tid  = threadIdx.x;
    const int lane = tid & 63;
    const int wave = tid >> 6;
    const int wy = wave >> 1, wx = wave & 1;
    const int rowBase = blockIdx.y * 128;   // a (Zj rows)
    const int colBase = blockIdx.x * 256;   // b (Zi rows)

    // --- staging: chunk = 8 rows x 128 B = 1 KB. A: 16 chunks (wave owns 4),
    //     B: 32 chunks (wave owns 8). lane -> row lane>>3, physical piece lane&7.
    const int lrow = lane >> 3;               // 0..7
    const int lp   = lane & 7;                // physical 16B piece
    const int lc   = (lp - lrow) & 7;         // logical piece (swizzle^-1)
    const unsigned char* gA[4]; unsigned char* sA[4];
    const unsigned char* gB[8]; unsigned char* sB[8];
    #pragma unroll
    for (int c = 0; c < 4; ++c) {
        gA[c] = Zj8 + (size_t)(rowBase + (4*wave + c)*8 + lrow) * D_DIM + lc*16;
        sA[c] = lA + (4*wave + c) * 1024;
    }
    #pragma unroll
    for (int c = 0; c < 8; ++c) {
        gB[c] = Zi8 + (size_t)(colBase + (8*wave + c)*8 + lrow) * D_DIM + lc*16;
        sB[c] = lB + (8*wave + c) * 1024;
    }

    // --- fragment addressing: lane needs k = kb*64 + h*32 + [0..31]
    //     (h = lane>>5) -> logical pieces c = kb*4 + h*2 + {0,1};
    //     physical p = (c + (lane&7)) & 7 (LDS row ≡ lane&31, row&7 = lane&7).
    const int r31 = lane & 31;
    const int h   = lane >> 5;
    int off[2][2];
    #pragma unroll
    for (int kb = 0; kb < 2; ++kb) {
        off[kb][0] = ((((kb << 2) + (h << 1) + 0) + (lane & 7)) & 7) * 16;
        off[kb][1] = ((((kb << 2) + (h << 1) + 1) + (lane & 7)) & 7) * 16;
    }
    const unsigned char* fA[2];
    #pragma unroll
    for (int ti = 0; ti < 2; ++ti) fA[ti] = lA + (wy*64 + ti*32 + r31) * 128;
    const unsigned char* fB[4];
    #pragma unroll
    for (int tj = 0; tj < 4; ++tj) fB[tj] = lB + (wx*128 + tj*32 + r31) * 128;

    f32x16 acc[2][4];
    #pragma unroll
    for (int ti = 0; ti < 2; ++ti)
        #pragma unroll
        for (int tj = 0; tj < 4; ++tj)
            #pragma unroll
            for (int r = 0; r < 16; ++r) acc[ti][tj][r] = 0.0f;

    for (int k0 = 0; k0 < D_DIM; k0 += 128) {
        __syncthreads();                    // prior readers done
        #pragma unroll
        for (int c = 0; c < 4; ++c) gload_lds16(gA[c] + k0, sA[c]);
        #pragma unroll
        for (int c = 0; c < 8; ++c) gload_lds16(gB[c] + k0, sB[c]);
        __syncthreads();                    // staging visible

        i32x8 a[2][2];
        #pragma unroll
        for (int ti = 0; ti < 2; ++ti)
            #pragma unroll
            for (int kb = 0; kb < 2; ++kb)
                a[ti][kb] = ld_frag(fA[ti], off[kb][0], off[kb][1]);

        #pragma unroll
        for (int tj = 0; tj < 4; ++tj) {
            #pragma unroll
            for (int kb = 0; kb < 2; ++kb) {
                i32x8 b = ld_frag(fB[tj], off[kb][0], off[kb][1]);
                #pragma unroll
                for (int ti = 0; ti < 2; ++ti)
                    acc[ti][tj] = __builtin_amdgcn_mfma_scale_f32_32x32x64_f8f6f4(
                        a[ti][kb], b, acc[ti][tj],
                        0, 0,                    // cbsz=fp8(e4m3), blgp=fp8
                        0, 0x7f7f7f7f,           // scale A: e8m0 127 = 1.0
                        0, 0x7f7f7f7f);          // scale B: 1.0
            }
        }
    }

    // --- fused epilogue; 32x32 C layout: col=lane&31,
    //     row = (reg&3) + 8*(reg>>2) + 4*(lane>>5)
    const int erow = rowBase + wy*64 + h*4;
    const int ecol = colBase + wx*128 + r31;
    float neg = 0.f, pos = 0.f;
    #pragma unroll
    for (int ti = 0; ti < 2; ++ti) {
        #pragma unroll
        for (int tj = 0; tj < 4; ++tj) {
            #pragma unroll
            for (int r = 0; r < 16; ++r) {
                const int row = erow + ti*32 + (r & 3) + 8*(r >> 2);
                const int col = ecol + tj*32;
                const float x = acc[ti][tj][r] * INV_S2 - TEMP;   // sim - T
                if (row == col) pos += __logf(1.0f + __expf(-x));
                else            neg += __logf(1.0f + __expf(x));
            }
        }
    }
    #pragma unroll
    for (int o = 32; o > 0; o >>= 1) {
        neg += __shfl_down(neg, o, 64);
        pos += __shfl_down(pos, o, 64);
    }
    if (lane == 0) { rn[wave] = neg; rp[wave] = pos; }
    __syncthreads();
    if (tid == 0) {
        atomicAdd(&w[1], rn[0] + rn[1] + rn[2] + rn[3]);
        if ((int)blockIdx.x == (int)(blockIdx.y >> 1))   // tile holding diagonal
            atomicAdd(&w[0], rp[0] + rp[1] + rp[2] + rp[3]);
        __threadfence();
        unsigned int done = atomicAdd(((unsigned int*)w) + 2, 1u);
        if (done == gridDim.x * gridDim.y - 1) {         // last block finalizes
            const float psum = atomicAdd(&w[0], 0.0f);
            const float nsum = atomicAdd(&w[1], 0.0f);
            out[0] = 0.5f * (psum / (float)B_ROWS)
                   + 0.5f * (nsum / ((float)B_ROWS * (float)(B_ROWS - 1)));
        }
    }
}

extern "C" void kernel_launch(void* const* d_in, const int* in_sizes, int n_in,
                              void* d_out, int out_size, void* d_ws, size_t ws_size,
                              hipStream_t stream) {
    const float* emb_i = (const float*)d_in[0];
    const float* emb_j = (const float*)d_in[1];
    float* w = (float*)d_ws;
    unsigned char* Zi8 = (unsigned char*)(w + 16);
    unsigned char* Zj8 = Zi8 + (size_t)B_ROWS * D_DIM;
    float* out = (float*)d_out;

    norm_cast_kernel<<<2 * B_ROWS / 4, 256, 0, stream>>>(emb_i, emb_j, Zi8, Zj8, w);
    dim3 grid(B_ROWS / 256, B_ROWS / 128);   // 16 x 32 = 512 blocks, 2/CU
    simloss_mxfp8_kernel<<<grid, 256, 0, stream>>>(Zi8, Zj8, w, out);
}

// Round 8
// 237.781 us; speedup vs baseline: 1.1725x; 1.1725x over previous
//
#include <hip/hip_runtime.h>
#include <math.h>

#define B_ROWS 4096
#define D_DIM  1024
static constexpr float TEMP = 0.2f;
static constexpr float FP8_SCALE = 16.0f;        // per-side scale before cast
static constexpr float INV_S2 = 1.0f / 256.0f;   // 1/SCALE^2: acc -> sim

typedef __attribute__((ext_vector_type(8))) int    i32x8;
typedef __attribute__((ext_vector_type(16))) float f32x16;

// float -> OCP e4m3fn byte, RNE. Data path: |f| <= ~4, no NaN/inf.
__device__ inline unsigned char f2fp8(float f) {
    unsigned int u = __float_as_uint(f);
    unsigned int s = (u >> 24) & 0x80u;
    float af = fabsf(f);
    unsigned char b;
    if (af >= 0x1.0p-6f) {                 // normal e4m3 range
        unsigned int au = u & 0x7fffffffu;
        unsigned int lsb = (au >> 20) & 1u;
        au += 0x7ffffu + lsb;              // RNE into 3 mantissa bits
        int e = (int)(au >> 23) - 127 + 7;
        unsigned int m = (au >> 20) & 7u;
        if (e > 15 || (e == 15 && m > 6)) b = 0x7e;   // saturate 448
        else b = (unsigned char)((e << 3) | m);
    } else {                               // subnormal: quantum 2^-9
        int q = (int)rintf(af * 512.0f);
        b = (unsigned char)(q >= 8 ? 0x08 : q);
    }
    return (unsigned char)(b | s);
}

__device__ inline unsigned int f2fp8x4(float4 v) {
    return (unsigned int)f2fp8(v.x)
         | ((unsigned int)f2fp8(v.y) << 8)
         | ((unsigned int)f2fp8(v.z) << 16)
         | ((unsigned int)f2fp8(v.w) << 24);
}

// async global->LDS, 16 B/lane; LDS dest = wave-uniform base + lane*16
__device__ inline void gload_lds16(const unsigned char* g, unsigned char* l) {
    __builtin_amdgcn_global_load_lds(
        (const __attribute__((address_space(1))) unsigned int*)g,
        (__attribute__((address_space(3))) unsigned int*)l,
        16, 0, 0);
}

// two ds_read_b128 -> one 8-VGPR fragment (regs 0..3 = lower 16 k-bytes)
__device__ inline i32x8 ld_frag(const unsigned char* row, int o0, int o1) {
    union { i32x8 v; int4 q[2]; } u;
    u.q[0] = *(const int4*)(row + o0);
    u.q[1] = *(const int4*)(row + o1);
    return u.v;
}

// ws layout: w[0]=pos acc, w[1]=neg acc, w[2]=finalize ticket (u32),
//            then Zi8 (4096x1024 fp8) at byte (w+16), Zj8 after.

// Wave-per-row normalize (fp32) + scale by 16 + cast to fp8 e4m3.
__global__ __launch_bounds__(256) void norm_cast_kernel(
        const float* __restrict__ emb_i, const float* __restrict__ emb_j,
        unsigned char* __restrict__ Zi8, unsigned char* __restrict__ Zj8,
        float* __restrict__ w) {
    const int tid = threadIdx.x;
    if (blockIdx.x == 0 && tid == 0) {
        w[0] = 0.0f; w[1] = 0.0f;
        ((unsigned int*)w)[2] = 0u;
    }
    const int wave = tid >> 6, lane = tid & 63;
    const int row = blockIdx.x * 4 + wave;          // 0..8191
    const float* src; unsigned char* dst; int r;
    if (row < B_ROWS) { src = emb_i; dst = Zi8; r = row; }
    else              { src = emb_j; dst = Zj8; r = row - B_ROWS; }

    const float4* p = (const float4*)(src + (size_t)r * D_DIM);
    float4 v0 = p[lane], v1 = p[64 + lane], v2 = p[128 + lane], v3 = p[192 + lane];
    float s = v0.x*v0.x + v0.y*v0.y + v0.z*v0.z + v0.w*v0.w
            + v1.x*v1.x + v1.y*v1.y + v1.z*v1.z + v1.w*v1.w
            + v2.x*v2.x + v2.y*v2.y + v2.z*v2.z + v2.w*v2.w
            + v3.x*v3.x + v3.y*v3.y + v3.z*v3.z + v3.w*v3.w;
    #pragma unroll
    for (int m = 1; m < 64; m <<= 1) s += __shfl_xor(s, m, 64);
    const float inv = FP8_SCALE / fmaxf(sqrtf(s), 1e-12f);

    float4 a0 = {v0.x*inv, v0.y*inv, v0.z*inv, v0.w*inv};
    float4 a1 = {v1.x*inv, v1.y*inv, v1.z*inv, v1.w*inv};
    float4 a2 = {v2.x*inv, v2.y*inv, v2.z*inv, v2.w*inv};
    float4 a3 = {v3.x*inv, v3.y*inv, v3.z*inv, v3.w*inv};
    unsigned int* q = (unsigned int*)(dst + (size_t)r * D_DIM);
    q[lane]       = f2fp8x4(a0);
    q[64 + lane]  = f2fp8x4(a1);
    q[128 + lane] = f2fp8x4(a2);
    q[192 + lane] = f2fp8x4(a3);
}

// 128x128 block tile, BK=128, 4 waves in 2x2; wave owns 64x64 = 2x2 tiles
// of 32x32 via mfma_scale_f32_32x32x64_f8f6f4 with unit e8m0 scales (pure
// fp8 matmul at 2x non-scaled rate).  acc = 2*2*16 = 64 regs/wave -- sized
// to fit __launch_bounds__(256,2)'s 256-reg cap WITHOUT spilling (R7's
// 64x128 wave tile spilled: 303 MB scratch WRITE_SIZE).
//
// LDS row = 128 B = 8 x 16B pieces, XOR swizzle p = (c + row&7) & 7.
// Staging (global_load_lds, lane*16 dest) fetches the swizzled *global*
// piece; fragment reads are ds_read_b128 (16B granularity, 2-way max).
__global__ __launch_bounds__(256, 2) void simloss_mxfp8_kernel(
        const unsigned char* __restrict__ Zi8,
        const unsigned char* __restrict__ Zj8,
        float* __restrict__ w, float* __restrict__ out) {
    __shared__ __align__(16) unsigned char lA[128 * 128];  // 16 KB (Zj rows)
    __shared__ __align__(16) unsigned char lB[128 * 128];  // 16 KB (Zi rows)
    __shared__ float rn[4], rp[4];

    const int tid  = threadIdx.x;
    const int lane = tid & 63;
    const int wave = tid >> 6;
    const int wy = wave >> 1, wx = wave & 1;
    const int rowBase = blockIdx.y * 128;   // a (Zj rows)
    const int colBase = blockIdx.x * 128;   // b (Zi rows)

    // --- staging: chunk = 8 rows x 128 B = 1 KB; 16 chunks per tile,
    //     wave owns chunks 4w..4w+3 of A and of B.
    const int lrow = lane >> 3;               // 0..7 row within chunk
    const int lp   = lane & 7;                // physical 16B piece
    const int lc   = (lp - lrow) & 7;         // logical piece (swizzle^-1)
    const unsigned char* gA[4]; unsigned char* sA[4];
    const unsigned char* gB[4]; unsigned char* sB[4];
    #pragma unroll
    for (int c = 0; c < 4; ++c) {
        const int ch = 4 * wave + c;
        gA[c] = Zj8 + (size_t)(rowBase + ch * 8 + lrow) * D_DIM + lc * 16;
        gB[c] = Zi8 + (size_t)(colBase + ch * 8 + lrow) * D_DIM + lc * 16;
        sA[c] = lA + ch * 1024;
        sB[c] = lB + ch * 1024;
    }

    // --- fragment addressing: lane needs k-bytes kb*64 + h*32 + [0..31]
    //     (h = lane>>5) = logical pieces kb*4 + h*2 + {0,1};
    //     physical p = (c + (row&7)) & 7, row&7 = lane&7.
    const int r31 = lane & 31;
    const int h   = lane >> 5;
    int off[2][2];
    #pragma unroll
    for (int kb = 0; kb < 2; ++kb) {
        off[kb][0] = ((((kb << 2) + (h << 1) + 0) + (lane & 7)) & 7) * 16;
        off[kb][1] = ((((kb << 2) + (h << 1) + 1) + (lane & 7)) & 7) * 16;
    }
    const unsigned char* fA[2];
    const unsigned char* fB[2];
    #pragma unroll
    for (int t = 0; t < 2; ++t) {
        fA[t] = lA + (wy * 64 + t * 32 + r31) * 128;
        fB[t] = lB + (wx * 64 + t * 32 + r31) * 128;
    }

    f32x16 acc[2][2];
    #pragma unroll
    for (int ti = 0; ti < 2; ++ti)
        #pragma unroll
        for (int tj = 0; tj < 2; ++tj)
            #pragma unroll
            for (int r = 0; r < 16; ++r) acc[ti][tj][r] = 0.0f;

    for (int k0 = 0; k0 < D_DIM; k0 += 128) {
        __syncthreads();                    // prior readers done
        #pragma unroll
        for (int c = 0; c < 4; ++c) {
            gload_lds16(gA[c] + k0, sA[c]);
            gload_lds16(gB[c] + k0, sB[c]);
        }
        __syncthreads();                    // staging visible

        #pragma unroll
        for (int kb = 0; kb < 2; ++kb) {
            i32x8 a0 = ld_frag(fA[0], off[kb][0], off[kb][1]);
            i32x8 a1 = ld_frag(fA[1], off[kb][0], off[kb][1]);
            i32x8 b0 = ld_frag(fB[0], off[kb][0], off[kb][1]);
            i32x8 b1 = ld_frag(fB[1], off[kb][0], off[kb][1]);
            acc[0][0] = __builtin_amdgcn_mfma_scale_f32_32x32x64_f8f6f4(
                a0, b0, acc[0][0], 0, 0, 0, 0x7f7f7f7f, 0, 0x7f7f7f7f);
            acc[0][1] = __builtin_amdgcn_mfma_scale_f32_32x32x64_f8f6f4(
                a0, b1, acc[0][1], 0, 0, 0, 0x7f7f7f7f, 0, 0x7f7f7f7f);
            acc[1][0] = __builtin_amdgcn_mfma_scale_f32_32x32x64_f8f6f4(
                a1, b0, acc[1][0], 0, 0, 0, 0x7f7f7f7f, 0, 0x7f7f7f7f);
            acc[1][1] = __builtin_amdgcn_mfma_scale_f32_32x32x64_f8f6f4(
                a1, b1, acc[1][1], 0, 0, 0, 0x7f7f7f7f, 0, 0x7f7f7f7f);
        }
    }

    // --- fused epilogue; 32x32 C layout: col=lane&31,
    //     row = (reg&3) + 8*(reg>>2) + 4*(lane>>5)   [verified R7]
    const int erow = rowBase + wy * 64 + h * 4;
    const int ecol = colBase + wx * 64 + r31;
    float neg = 0.f, pos = 0.f;
    #pragma unroll
    for (int ti = 0; ti < 2; ++ti) {
        #pragma unroll
        for (int tj = 0; tj < 2; ++tj) {
            #pragma unroll
            for (int r = 0; r < 16; ++r) {
                const int row = erow + ti * 32 + (r & 3) + 8 * (r >> 2);
                const int col = ecol + tj * 32;
                const float x = acc[ti][tj][r] * INV_S2 - TEMP;   // sim - T
                if (row == col) pos += __logf(1.0f + __expf(-x));
                else            neg += __logf(1.0f + __expf(x));
            }
        }
    }
    #pragma unroll
    for (int o = 32; o > 0; o >>= 1) {
        neg += __shfl_down(neg, o, 64);
        pos += __shfl_down(pos, o, 64);
    }
    if (lane == 0) { rn[wave] = neg; rp[wave] = pos; }
    __syncthreads();
    if (tid == 0) {
        atomicAdd(&w[1], rn[0] + rn[1] + rn[2] + rn[3]);
        if (blockIdx.x == blockIdx.y)       // diagonal tile
            atomicAdd(&w[0], rp[0] + rp[1] + rp[2] + rp[3]);
        __threadfence();
        unsigned int done = atomicAdd(((unsigned int*)w) + 2, 1u);
        if (done == gridDim.x * gridDim.y - 1) {   // last block finalizes
            const float psum = atomicAdd(&w[0], 0.0f);
            const float nsum = atomicAdd(&w[1], 0.0f);
            out[0] = 0.5f * (psum / (float)B_ROWS)
                   + 0.5f * (nsum / ((float)B_ROWS * (float)(B_ROWS - 1)));
        }
    }
}

extern "C" void kernel_launch(void* const* d_in, const int* in_sizes, int n_in,
                              void* d_out, int out_size, void* d_ws, size_t ws_size,
                              hipStream_t stream) {
    const float* emb_i = (const float*)d_in[0];
    const float* emb_j = (const float*)d_in[1];
    float* w = (float*)d_ws;
    unsigned char* Zi8 = (unsigned char*)(w + 16);
    unsigned char* Zj8 = Zi8 + (size_t)B_ROWS * D_DIM;
    float* out = (float*)d_out;

    norm_cast_kernel<<<2 * B_ROWS / 4, 256, 0, stream>>>(emb_i, emb_j, Zi8, Zj8, w);
    dim3 grid(B_ROWS / 128, B_ROWS / 128);   // 32 x 32 = 1024 blocks
    simloss_mxfp8_kernel<<<grid, 256, 0, stream>>>(Zi8, Zj8, w, out);
}

// Round 9
// 182.798 us; speedup vs baseline: 1.5252x; 1.3008x over previous
//
#include <hip/hip_runtime.h>
#include <math.h>

#define B_ROWS 4096
#define D_DIM  1024
static constexpr float TEMP = 0.2f;
static constexpr float FP8_SCALE = 16.0f;        // per-side scale before cast
static constexpr float INV_S2 = 1.0f / 256.0f;   // 1/SCALE^2: acc -> sim

typedef __attribute__((ext_vector_type(8))) int    i32x8;
typedef __attribute__((ext_vector_type(16))) float f32x16;

// float -> OCP e4m3fn byte, RNE. Data path: |f| <= ~4, no NaN/inf.
__device__ inline unsigned char f2fp8(float f) {
    unsigned int u = __float_as_uint(f);
    unsigned int s = (u >> 24) & 0x80u;
    float af = fabsf(f);
    unsigned char b;
    if (af >= 0x1.0p-6f) {                 // normal e4m3 range
        unsigned int au = u & 0x7fffffffu;
        unsigned int lsb = (au >> 20) & 1u;
        au += 0x7ffffu + lsb;              // RNE into 3 mantissa bits
        int e = (int)(au >> 23) - 127 + 7;
        unsigned int m = (au >> 20) & 7u;
        if (e > 15 || (e == 15 && m > 6)) b = 0x7e;   // saturate 448
        else b = (unsigned char)((e << 3) | m);
    } else {                               // subnormal: quantum 2^-9
        int q = (int)rintf(af * 512.0f);
        b = (unsigned char)(q >= 8 ? 0x08 : q);
    }
    return (unsigned char)(b | s);
}

__device__ inline unsigned int f2fp8x4(float4 v) {
    return (unsigned int)f2fp8(v.x)
         | ((unsigned int)f2fp8(v.y) << 8)
         | ((unsigned int)f2fp8(v.z) << 16)
         | ((unsigned int)f2fp8(v.w) << 24);
}

// async global->LDS, 16 B/lane; LDS dest = wave-uniform base + lane*16
__device__ inline void gload_lds16(const unsigned char* g, unsigned char* l) {
    __builtin_amdgcn_global_load_lds(
        (const __attribute__((address_space(1))) unsigned int*)g,
        (__attribute__((address_space(3))) unsigned int*)l,
        16, 0, 0);
}

// two ds_read_b128 -> one 8-VGPR fragment (regs 0..3 = lower 16 k-bytes)
__device__ inline i32x8 ld_frag(const unsigned char* row, int o0, int o1) {
    union { i32x8 v; int4 q[2]; } u;
    u.q[0] = *(const int4*)(row + o0);
    u.q[1] = *(const int4*)(row + o1);
    return u.v;
}

// ws layout: w[0]=pos acc, w[1]=neg acc, w[2]=finalize ticket (u32),
//            then Zi8 (4096x1024 fp8) at byte (w+16), Zj8 after.

// Wave-per-row normalize (fp32) + scale by 16 + cast to fp8 e4m3.
__global__ __launch_bounds__(256) void norm_cast_kernel(
        const float* __restrict__ emb_i, const float* __restrict__ emb_j,
        unsigned char* __restrict__ Zi8, unsigned char* __restrict__ Zj8,
        float* __restrict__ w) {
    const int tid = threadIdx.x;
    if (blockIdx.x == 0 && tid == 0) {
        w[0] = 0.0f; w[1] = 0.0f;
        ((unsigned int*)w)[2] = 0u;
    }
    const int wave = tid >> 6, lane = tid & 63;
    const int row = blockIdx.x * 4 + wave;          // 0..8191
    const float* src; unsigned char* dst; int r;
    if (row < B_ROWS) { src = emb_i; dst = Zi8; r = row; }
    else              { src = emb_j; dst = Zj8; r = row - B_ROWS; }

    const float4* p = (const float4*)(src + (size_t)r * D_DIM);
    float4 v0 = p[lane], v1 = p[64 + lane], v2 = p[128 + lane], v3 = p[192 + lane];
    float s = v0.x*v0.x + v0.y*v0.y + v0.z*v0.z + v0.w*v0.w
            + v1.x*v1.x + v1.y*v1.y + v1.z*v1.z + v1.w*v1.w
            + v2.x*v2.x + v2.y*v2.y + v2.z*v2.z + v2.w*v2.w
            + v3.x*v3.x + v3.y*v3.y + v3.z*v3.z + v3.w*v3.w;
    #pragma unroll
    for (int m = 1; m < 64; m <<= 1) s += __shfl_xor(s, m, 64);
    const float inv = FP8_SCALE / fmaxf(sqrtf(s), 1e-12f);

    float4 a0 = {v0.x*inv, v0.y*inv, v0.z*inv, v0.w*inv};
    float4 a1 = {v1.x*inv, v1.y*inv, v1.z*inv, v1.w*inv};
    float4 a2 = {v2.x*inv, v2.y*inv, v2.z*inv, v2.w*inv};
    float4 a3 = {v3.x*inv, v3.y*inv, v3.z*inv, v3.w*inv};
    unsigned int* q = (unsigned int*)(dst + (size_t)r * D_DIM);
    q[lane]       = f2fp8x4(a0);
    q[64 + lane]  = f2fp8x4(a1);
    q[128 + lane] = f2fp8x4(a2);
    q[192 + lane] = f2fp8x4(a3);
}

// 128x256 block tile, BK=128, 4 waves in 2x2; wave owns 64x128 = 2x4 tiles
// of 32x32 via mfma_scale_f32_32x32x64_f8f6f4 with unit e8m0 scales.
// NOTE: NO min-waves in __launch_bounds__ — R7/R8 proved that (256,2)
// forces a 128-arch-VGPR split and mfma_scale's operands then spill
// (303/328 MB scratch WRITE_SIZE). Uncapped, demand ~220 regs ->
// 2 waves/SIMD = 2 blocks/CU, same occupancy, no spill.
//
// LDS row = 128 B = 8 x 16B pieces, XOR swizzle p = (c + row&7) & 7.
// Staging (global_load_lds, lane*16 dest) fetches the swizzled *global*
// piece; fragment reads are ds_read_b128 (16B granularity).
__global__ __launch_bounds__(256) void simloss_mxfp8_kernel(
        const unsigned char* __restrict__ Zi8,
        const unsigned char* __restrict__ Zj8,
        float* __restrict__ w, float* __restrict__ out) {
    __shared__ __align__(16) unsigned char lA[128 * 128];  // 16 KB (Zj rows)
    __shared__ __align__(16) unsigned char lB[256 * 128];  // 32 KB (Zi rows)
    __shared__ float rn[4], rp[4];

    const int tid  = threadIdx.x;
    const int lane = tid & 63;
    const int wave = tid >> 6;
    const int wy = wave >> 1, wx = wave & 1;
    const int rowBase = blockIdx.y * 128;   // a (Zj rows)
    const int colBase = blockIdx.x * 256;   // b (Zi rows)

    // --- staging: chunk = 8 rows x 128 B = 1 KB. A: 16 chunks (wave owns 4),
    //     B: 32 chunks (wave owns 8). lane -> row lane>>3, physical piece lane&7.
    const int lrow = lane >> 3;               // 0..7
    const int lp   = lane & 7;                // physical 16B piece
    const int lc   = (lp - lrow) & 7;         // logical piece (swizzle^-1)
    const unsigned char* gA[4]; unsigned char* sA[4];
    const unsigned char* gB[8]; unsigned char* sB[8];
    #pragma unroll
    for (int c = 0; c < 4; ++c) {
        gA[c] = Zj8 + (size_t)(rowBase + (4*wave + c)*8 + lrow) * D_DIM + lc*16;
        sA[c] = lA + (4*wave + c) * 1024;
    }
    #pragma unroll
    for (int c = 0; c < 8; ++c) {
        gB[c] = Zi8 + (size_t)(colBase + (8*wave + c)*8 + lrow) * D_DIM + lc*16;
        sB[c] = lB + (8*wave + c) * 1024;
    }

    // --- fragment addressing: lane needs k = kb*64 + h*32 + [0..31]
    //     (h = lane>>5) -> logical pieces c = kb*4 + h*2 + {0,1};
    //     physical p = (c + (lane&7)) & 7 (LDS row ≡ lane&31, row&7 = lane&7).
    const int r31 = lane & 31;
    const int h   = lane >> 5;
    int off[2][2];
    #pragma unroll
    for (int kb = 0; kb < 2; ++kb) {
        off[kb][0] = ((((kb << 2) + (h << 1) + 0) + (lane & 7)) & 7) * 16;
        off[kb][1] = ((((kb << 2) + (h << 1) + 1) + (lane & 7)) & 7) * 16;
    }
    const unsigned char* fA[2];
    #pragma unroll
    for (int ti = 0; ti < 2; ++ti) fA[ti] = lA + (wy*64 + ti*32 + r31) * 128;
    const unsigned char* fB[4];
    #pragma unroll
    for (int tj = 0; tj < 4; ++tj) fB[tj] = lB + (wx*128 + tj*32 + r31) * 128;

    f32x16 acc[2][4];
    #pragma unroll
    for (int ti = 0; ti < 2; ++ti)
        #pragma unroll
        for (int tj = 0; tj < 4; ++tj)
            #pragma unroll
            for (int r = 0; r < 16; ++r) acc[ti][tj][r] = 0.0f;

    for (int k0 = 0; k0 < D_DIM; k0 += 128) {
        __syncthreads();                    // prior readers done
        #pragma unroll
        for (int c = 0; c < 4; ++c) gload_lds16(gA[c] + k0, sA[c]);
        #pragma unroll
        for (int c = 0; c < 8; ++c) gload_lds16(gB[c] + k0, sB[c]);
        __syncthreads();                    // staging visible

        i32x8 a[2][2];
        #pragma unroll
        for (int ti = 0; ti < 2; ++ti)
            #pragma unroll
            for (int kb = 0; kb < 2; ++kb)
                a[ti][kb] = ld_frag(fA[ti], off[kb][0], off[kb][1]);

        #pragma unroll
        for (int tj = 0; tj < 4; ++tj) {
            #pragma unroll
            for (int kb = 0; kb < 2; ++kb) {
                i32x8 b = ld_frag(fB[tj], off[kb][0], off[kb][1]);
                #pragma unroll
                for (int ti = 0; ti < 2; ++ti)
                    acc[ti][tj] = __builtin_amdgcn_mfma_scale_f32_32x32x64_f8f6f4(
                        a[ti][kb], b, acc[ti][tj],
                        0, 0,                    // cbsz=fp8(e4m3), blgp=fp8
                        0, 0x7f7f7f7f,           // scale A: e8m0 127 = 1.0
                        0, 0x7f7f7f7f);          // scale B: 1.0
            }
        }
    }

    // --- fused epilogue; 32x32 C layout: col=lane&31,
    //     row = (reg&3) + 8*(reg>>2) + 4*(lane>>5)   [verified R7/R8]
    const int erow = rowBase + wy*64 + h*4;
    const int ecol = colBase + wx*128 + r31;
    float neg = 0.f, pos = 0.f;
    #pragma unroll
    for (int ti = 0; ti < 2; ++ti) {
        #pragma unroll
        for (int tj = 0; tj < 4; ++tj) {
            #pragma unroll
            for (int r = 0; r < 16; ++r) {
                const int row = erow + ti*32 + (r & 3) + 8*(r >> 2);
                const int col = ecol + tj*32;
                const float x = acc[ti][tj][r] * INV_S2 - TEMP;   // sim - T
                if (row == col) pos += __logf(1.0f + __expf(-x));
                else            neg += __logf(1.0f + __expf(x));
            }
        }
    }
    #pragma unroll
    for (int o = 32; o > 0; o >>= 1) {
        neg += __shfl_down(neg, o, 64);
        pos += __shfl_down(pos, o, 64);
    }
    if (lane == 0) { rn[wave] = neg; rp[wave] = pos; }
    __syncthreads();
    if (tid == 0) {
        atomicAdd(&w[1], rn[0] + rn[1] + rn[2] + rn[3]);
        if ((int)blockIdx.x == (int)(blockIdx.y >> 1))   // tile holding diagonal
            atomicAdd(&w[0], rp[0] + rp[1] + rp[2] + rp[3]);
        __threadfence();
        unsigned int done = atomicAdd(((unsigned int*)w) + 2, 1u);
        if (done == gridDim.x * gridDim.y - 1) {         // last block finalizes
            const float psum = atomicAdd(&w[0], 0.0f);
            const float nsum = atomicAdd(&w[1], 0.0f);
            out[0] = 0.5f * (psum / (float)B_ROWS)
                   + 0.5f * (nsum / ((float)B_ROWS * (float)(B_ROWS - 1)));
        }
    }
}

extern "C" void kernel_launch(void* const* d_in, const int* in_sizes, int n_in,
                              void* d_out, int out_size, void* d_ws, size_t ws_size,
                              hipStream_t stream) {
    const float* emb_i = (const float*)d_in[0];
    const float* emb_j = (const float*)d_in[1];
    float* w = (float*)d_ws;
    unsigned char* Zi8 = (unsigned char*)(w + 16);
    unsigned char* Zj8 = Zi8 + (size_t)B_ROWS * D_DIM;
    float* out = (float*)d_out;

    norm_cast_kernel<<<2 * B_ROWS / 4, 256, 0, stream>>>(emb_i, emb_j, Zi8, Zj8, w);
    dim3 grid(B_ROWS / 256, B_ROWS / 128);   // 16 x 32 = 512 blocks, 2/CU
    simloss_mxfp8_kernel<<<grid, 256, 0, stream>>>(Zi8, Zj8, w, out);
}

// Round 10
// 164.798 us; speedup vs baseline: 1.6918x; 1.1092x over previous
//
#include <hip/hip_runtime.h>
#include <math.h>

#define B_ROWS 4096
#define D_DIM  1024
static constexpr float TEMP = 0.2f;
static constexpr float FP8_SCALE = 16.0f;        // per-side scale before cast
static constexpr float INV_S2 = 1.0f / 256.0f;   // 1/SCALE^2: acc -> sim

typedef __attribute__((ext_vector_type(8))) int    i32x8;
typedef __attribute__((ext_vector_type(16))) float f32x16;

// float -> OCP e4m3fn byte, RNE. Data path: |f| <= ~4, no NaN/inf.
__device__ inline unsigned char f2fp8(float f) {
    unsigned int u = __float_as_uint(f);
    unsigned int s = (u >> 24) & 0x80u;
    float af = fabsf(f);
    unsigned char b;
    if (af >= 0x1.0p-6f) {                 // normal e4m3 range
        unsigned int au = u & 0x7fffffffu;
        unsigned int lsb = (au >> 20) & 1u;
        au += 0x7ffffu + lsb;              // RNE into 3 mantissa bits
        int e = (int)(au >> 23) - 127 + 7;
        unsigned int m = (au >> 20) & 7u;
        if (e > 15 || (e == 15 && m > 6)) b = 0x7e;   // saturate 448
        else b = (unsigned char)((e << 3) | m);
    } else {                               // subnormal: quantum 2^-9
        int q = (int)rintf(af * 512.0f);
        b = (unsigned char)(q >= 8 ? 0x08 : q);
    }
    return (unsigned char)(b | s);
}

__device__ inline unsigned int f2fp8x4(float4 v) {
    return (unsigned int)f2fp8(v.x)
         | ((unsigned int)f2fp8(v.y) << 8)
         | ((unsigned int)f2fp8(v.z) << 16)
         | ((unsigned int)f2fp8(v.w) << 24);
}

// async global->LDS, 16 B/lane; LDS dest = wave-uniform base + lane*16
__device__ inline void gload_lds16(const unsigned char* g, unsigned char* l) {
    __builtin_amdgcn_global_load_lds(
        (const __attribute__((address_space(1))) unsigned int*)g,
        (__attribute__((address_space(3))) unsigned int*)l,
        16, 0, 0);
}

// two ds_read_b128 -> one 8-VGPR fragment (regs 0..3 = lower 16 k-bytes)
__device__ inline i32x8 ld_frag(const unsigned char* row, int o0, int o1) {
    union { i32x8 v; int4 q[2]; } u;
    u.q[0] = *(const int4*)(row + o0);
    u.q[1] = *(const int4*)(row + o1);
    return u.v;
}

// ws layout: w[0]=pos acc, w[1]=neg acc, w[2]=finalize ticket (u32),
//            then Zi8 (4096x1024 fp8) at byte (w+16), Zj8 after.

// Wave-per-row normalize (fp32) + scale by 16 + cast to fp8 e4m3.
__global__ __launch_bounds__(256) void norm_cast_kernel(
        const float* __restrict__ emb_i, const float* __restrict__ emb_j,
        unsigned char* __restrict__ Zi8, unsigned char* __restrict__ Zj8,
        float* __restrict__ w) {
    const int tid = threadIdx.x;
    if (blockIdx.x == 0 && tid == 0) {
        w[0] = 0.0f; w[1] = 0.0f;
        ((unsigned int*)w)[2] = 0u;
    }
    const int wave = tid >> 6, lane = tid & 63;
    const int row = blockIdx.x * 4 + wave;          // 0..8191
    const float* src; unsigned char* dst; int r;
    if (row < B_ROWS) { src = emb_i; dst = Zi8; r = row; }
    else              { src = emb_j; dst = Zj8; r = row - B_ROWS; }

    const float4* p = (const float4*)(src + (size_t)r * D_DIM);
    float4 v0 = p[lane], v1 = p[64 + lane], v2 = p[128 + lane], v3 = p[192 + lane];
    float s = v0.x*v0.x + v0.y*v0.y + v0.z*v0.z + v0.w*v0.w
            + v1.x*v1.x + v1.y*v1.y + v1.z*v1.z + v1.w*v1.w
            + v2.x*v2.x + v2.y*v2.y + v2.z*v2.z + v2.w*v2.w
            + v3.x*v3.x + v3.y*v3.y + v3.z*v3.z + v3.w*v3.w;
    #pragma unroll
    for (int m = 1; m < 64; m <<= 1) s += __shfl_xor(s, m, 64);
    const float inv = FP8_SCALE / fmaxf(sqrtf(s), 1e-12f);

    float4 a0 = {v0.x*inv, v0.y*inv, v0.z*inv, v0.w*inv};
    float4 a1 = {v1.x*inv, v1.y*inv, v1.z*inv, v1.w*inv};
    float4 a2 = {v2.x*inv, v2.y*inv, v2.z*inv, v2.w*inv};
    float4 a3 = {v3.x*inv, v3.y*inv, v3.z*inv, v3.w*inv};
    unsigned int* q = (unsigned int*)(dst + (size_t)r * D_DIM);
    q[lane]       = f2fp8x4(a0);
    q[64 + lane]  = f2fp8x4(a1);
    q[128 + lane] = f2fp8x4(a2);
    q[192 + lane] = f2fp8x4(a3);
}

// 128x128 block tile, BK=128, 4 waves in 2x2; wave owns 64x64 = 2x2 tiles
// of 32x32 via mfma_scale_f32_32x32x64_f8f6f4 with unit e8m0 scales.
//
// Register accounting (the 3-round spill saga):
//   R7/R9: 64x128 wave tile -> acc 128 + hoisted B-frags 64 + A 32 + addr
//          ~60 > 256-reg wall -> spills at ANY launch bound. Infeasible.
//   R8:    64x64 tile capped (256,2) -> 128 arch-VGPR split -> spill.
//   NOW:   64x64 tile UNCAPPED: demand ~160-190 < 256 -> no spill,
//          2 waves/SIMD anyway (same occupancy the cap was buying).
//
// LDS row = 128 B = 8 x 16B pieces, XOR swizzle p = (c + row&7) & 7.
// Staging (global_load_lds, lane*16 dest) fetches the swizzled *global*
// piece; fragment reads are ds_read_b128 (16B granularity, 2-way max).
__global__ __launch_bounds__(256) void simloss_mxfp8_kernel(
        const unsigned char* __restrict__ Zi8,
        const unsigned char* __restrict__ Zj8,
        float* __restrict__ w, float* __restrict__ out) {
    __shared__ __align__(16) unsigned char lA[128 * 128];  // 16 KB (Zj rows)
    __shared__ __align__(16) unsigned char lB[128 * 128];  // 16 KB (Zi rows)
    __shared__ float rn[4], rp[4];

    const int tid  = threadIdx.x;
    const int lane = tid & 63;
    const int wave = tid >> 6;
    const int wy = wave >> 1, wx = wave & 1;
    const int rowBase = blockIdx.y * 128;   // a (Zj rows)
    const int colBase = blockIdx.x * 128;   // b (Zi rows)

    // --- staging: chunk = 8 rows x 128 B = 1 KB; 16 chunks per tile,
    //     wave owns chunks 4w..4w+3 of A and of B.
    const int lrow = lane >> 3;               // 0..7 row within chunk
    const int lp   = lane & 7;                // physical 16B piece
    const int lc   = (lp - lrow) & 7;         // logical piece (swizzle^-1)
    const unsigned char* gA[4]; unsigned char* sA[4];
    const unsigned char* gB[4]; unsigned char* sB[4];
    #pragma unroll
    for (int c = 0; c < 4; ++c) {
        const int ch = 4 * wave + c;
        gA[c] = Zj8 + (size_t)(rowBase + ch * 8 + lrow) * D_DIM + lc * 16;
        gB[c] = Zi8 + (size_t)(colBase + ch * 8 + lrow) * D_DIM + lc * 16;
        sA[c] = lA + ch * 1024;
        sB[c] = lB + ch * 1024;
    }

    // --- fragment addressing: lane needs k-bytes kb*64 + h*32 + [0..31]
    //     (h = lane>>5) = logical pieces kb*4 + h*2 + {0,1};
    //     physical p = (c + (row&7)) & 7, row&7 = lane&7.
    const int r31 = lane & 31;
    const int h   = lane >> 5;
    int off[2][2];
    #pragma unroll
    for (int kb = 0; kb < 2; ++kb) {
        off[kb][0] = ((((kb << 2) + (h << 1) + 0) + (lane & 7)) & 7) * 16;
        off[kb][1] = ((((kb << 2) + (h << 1) + 1) + (lane & 7)) & 7) * 16;
    }
    const unsigned char* fA[2];
    const unsigned char* fB[2];
    #pragma unroll
    for (int t = 0; t < 2; ++t) {
        fA[t] = lA + (wy * 64 + t * 32 + r31) * 128;
        fB[t] = lB + (wx * 64 + t * 32 + r31) * 128;
    }

    f32x16 acc[2][2];
    #pragma unroll
    for (int ti = 0; ti < 2; ++ti)
        #pragma unroll
        for (int tj = 0; tj < 2; ++tj)
            #pragma unroll
            for (int r = 0; r < 16; ++r) acc[ti][tj][r] = 0.0f;

    for (int k0 = 0; k0 < D_DIM; k0 += 128) {
        __syncthreads();                    // prior readers done
        #pragma unroll
        for (int c = 0; c < 4; ++c) {
            gload_lds16(gA[c] + k0, sA[c]);
            gload_lds16(gB[c] + k0, sB[c]);
        }
        __syncthreads();                    // staging visible

        #pragma unroll
        for (int kb = 0; kb < 2; ++kb) {
            i32x8 a0 = ld_frag(fA[0], off[kb][0], off[kb][1]);
            i32x8 a1 = ld_frag(fA[1], off[kb][0], off[kb][1]);
            i32x8 b0 = ld_frag(fB[0], off[kb][0], off[kb][1]);
            i32x8 b1 = ld_frag(fB[1], off[kb][0], off[kb][1]);
            acc[0][0] = __builtin_amdgcn_mfma_scale_f32_32x32x64_f8f6f4(
                a0, b0, acc[0][0], 0, 0, 0, 0x7f7f7f7f, 0, 0x7f7f7f7f);
            acc[0][1] = __builtin_amdgcn_mfma_scale_f32_32x32x64_f8f6f4(
                a0, b1, acc[0][1], 0, 0, 0, 0x7f7f7f7f, 0, 0x7f7f7f7f);
            acc[1][0] = __builtin_amdgcn_mfma_scale_f32_32x32x64_f8f6f4(
                a1, b0, acc[1][0], 0, 0, 0, 0x7f7f7f7f, 0, 0x7f7f7f7f);
            acc[1][1] = __builtin_amdgcn_mfma_scale_f32_32x32x64_f8f6f4(
                a1, b1, acc[1][1], 0, 0, 0, 0x7f7f7f7f, 0, 0x7f7f7f7f);
        }
    }

    // --- fused epilogue; 32x32 C layout: col=lane&31,
    //     row = (reg&3) + 8*(reg>>2) + 4*(lane>>5)   [verified R7/R8/R9]
    const int erow = rowBase + wy * 64 + h * 4;
    const int ecol = colBase + wx * 64 + r31;
    float neg = 0.f, pos = 0.f;
    #pragma unroll
    for (int ti = 0; ti < 2; ++ti) {
        #pragma unroll
        for (int tj = 0; tj < 2; ++tj) {
            #pragma unroll
            for (int r = 0; r < 16; ++r) {
                const int row = erow + ti * 32 + (r & 3) + 8 * (r >> 2);
                const int col = ecol + tj * 32;
                const float x = acc[ti][tj][r] * INV_S2 - TEMP;   // sim - T
                if (row == col) pos += __logf(1.0f + __expf(-x));
                else            neg += __logf(1.0f + __expf(x));
            }
        }
    }
    #pragma unroll
    for (int o = 32; o > 0; o >>= 1) {
        neg += __shfl_down(neg, o, 64);
        pos += __shfl_down(pos, o, 64);
    }
    if (lane == 0) { rn[wave] = neg; rp[wave] = pos; }
    __syncthreads();
    if (tid == 0) {
        atomicAdd(&w[1], rn[0] + rn[1] + rn[2] + rn[3]);
        if (blockIdx.x == blockIdx.y)       // diagonal tile
            atomicAdd(&w[0], rp[0] + rp[1] + rp[2] + rp[3]);
        __threadfence();
        unsigned int done = atomicAdd(((unsigned int*)w) + 2, 1u);
        if (done == gridDim.x * gridDim.y - 1) {   // last block finalizes
            const float psum = atomicAdd(&w[0], 0.0f);
            const float nsum = atomicAdd(&w[1], 0.0f);
            out[0] = 0.5f * (psum / (float)B_ROWS)
                   + 0.5f * (nsum / ((float)B_ROWS * (float)(B_ROWS - 1)));
        }
    }
}

extern "C" void kernel_launch(void* const* d_in, const int* in_sizes, int n_in,
                              void* d_out, int out_size, void* d_ws, size_t ws_size,
                              hipStream_t stream) {
    const float* emb_i = (const float*)d_in[0];
    const float* emb_j = (const float*)d_in[1];
    float* w = (float*)d_ws;
    unsigned char* Zi8 = (unsigned char*)(w + 16);
    unsigned char* Zj8 = Zi8 + (size_t)B_ROWS * D_DIM;
    float* out = (float*)d_out;

    norm_cast_kernel<<<2 * B_ROWS / 4, 256, 0, stream>>>(emb_i, emb_j, Zi8, Zj8, w);
    dim3 grid(B_ROWS / 128, B_ROWS / 128);   // 32 x 32 = 1024 blocks
    simloss_mxfp8_kernel<<<grid, 256, 0, stream>>>(Zi8, Zj8, w, out);
}

// Round 11
// 128.781 us; speedup vs baseline: 2.1650x; 1.2797x over previous
//
#include <hip/hip_runtime.h>
#include <math.h>

#define B_ROWS 4096
#define D_DIM  1024
static constexpr float TEMP = 0.2f;
static constexpr float FP8_SCALE = 16.0f;        // per-side scale before cast
static constexpr float INV_S2 = 1.0f / 256.0f;   // 1/SCALE^2: acc -> sim

typedef __attribute__((ext_vector_type(8))) int    i32x8;
typedef __attribute__((ext_vector_type(16))) float f32x16;

// float -> OCP e4m3fn byte, RNE. Data path: |f| <= ~4, no NaN/inf.
__device__ inline unsigned char f2fp8(float f) {
    unsigned int u = __float_as_uint(f);
    unsigned int s = (u >> 24) & 0x80u;
    float af = fabsf(f);
    unsigned char b;
    if (af >= 0x1.0p-6f) {                 // normal e4m3 range
        unsigned int au = u & 0x7fffffffu;
        unsigned int lsb = (au >> 20) & 1u;
        au += 0x7ffffu + lsb;              // RNE into 3 mantissa bits
        int e = (int)(au >> 23) - 127 + 7;
        unsigned int m = (au >> 20) & 7u;
        if (e > 15 || (e == 15 && m > 6)) b = 0x7e;   // saturate 448
        else b = (unsigned char)((e << 3) | m);
    } else {                               // subnormal: quantum 2^-9
        int q = (int)rintf(af * 512.0f);
        b = (unsigned char)(q >= 8 ? 0x08 : q);
    }
    return (unsigned char)(b | s);
}

__device__ inline unsigned int f2fp8x4(float4 v) {
    return (unsigned int)f2fp8(v.x)
         | ((unsigned int)f2fp8(v.y) << 8)
         | ((unsigned int)f2fp8(v.z) << 16)
         | ((unsigned int)f2fp8(v.w) << 24);
}

// async global->LDS, 16 B/lane; LDS dest = wave-uniform base + lane*16
__device__ inline void gload_lds16(const unsigned char* g, unsigned char* l) {
    __builtin_amdgcn_global_load_lds(
        (const __attribute__((address_space(1))) unsigned int*)g,
        (__attribute__((address_space(3))) unsigned int*)l,
        16, 0, 0);
}

// two ds_read_b128 -> one 8-VGPR fragment; no union (element inserts only)
__device__ inline i32x8 ld_frag(const unsigned char* row, int o0, int o1) {
    int4 lo = *(const int4*)(row + o0);
    int4 hi = *(const int4*)(row + o1);
    i32x8 v;
    v[0] = lo.x; v[1] = lo.y; v[2] = lo.z; v[3] = lo.w;
    v[4] = hi.x; v[5] = hi.y; v[6] = hi.z; v[7] = hi.w;
    return v;
}

// epilogue helper: one 32x32 C tile (verified layout: col = lane&31,
// row = (reg&3) + 8*(reg>>2) + 4*(lane>>5))
__device__ inline void acc_tile(const f32x16 a, int row0, int col,
                                float& neg, float& pos) {
    #pragma unroll
    for (int r = 0; r < 16; ++r) {
        const int row = row0 + (r & 3) + 8 * (r >> 2);
        const float x = a[r] * INV_S2 - TEMP;   // sim - T
        if (row == col) pos += __logf(1.0f + __expf(-x));
        else            neg += __logf(1.0f + __expf(x));
    }
}

// ws layout: w[0]=pos acc, w[1]=neg acc, w[2]=finalize ticket (u32),
//            then Zi8 (4096x1024 fp8) at byte (w+16), Zj8 after.

// Wave-per-row normalize (fp32) + scale by 16 + cast to fp8 e4m3.
__global__ __launch_bounds__(256) void norm_cast_kernel(
        const float* __restrict__ emb_i, const float* __restrict__ emb_j,
        unsigned char* __restrict__ Zi8, unsigned char* __restrict__ Zj8,
        float* __restrict__ w) {
    const int tid = threadIdx.x;
    if (blockIdx.x == 0 && tid == 0) {
        w[0] = 0.0f; w[1] = 0.0f;
        ((unsigned int*)w)[2] = 0u;
    }
    const int wave = tid >> 6, lane = tid & 63;
    const int row = blockIdx.x * 4 + wave;          // 0..8191
    const float* src; unsigned char* dst; int r;
    if (row < B_ROWS) { src = emb_i; dst = Zi8; r = row; }
    else              { src = emb_j; dst = Zj8; r = row - B_ROWS; }

    const float4* p = (const float4*)(src + (size_t)r * D_DIM);
    float4 v0 = p[lane], v1 = p[64 + lane], v2 = p[128 + lane], v3 = p[192 + lane];
    float s = v0.x*v0.x + v0.y*v0.y + v0.z*v0.z + v0.w*v0.w
            + v1.x*v1.x + v1.y*v1.y + v1.z*v1.z + v1.w*v1.w
            + v2.x*v2.x + v2.y*v2.y + v2.z*v2.z + v2.w*v2.w
            + v3.x*v3.x + v3.y*v3.y + v3.z*v3.z + v3.w*v3.w;
    #pragma unroll
    for (int m = 1; m < 64; m <<= 1) s += __shfl_xor(s, m, 64);
    const float inv = FP8_SCALE / fmaxf(sqrtf(s), 1e-12f);

    float4 a0 = {v0.x*inv, v0.y*inv, v0.z*inv, v0.w*inv};
    float4 a1 = {v1.x*inv, v1.y*inv, v1.z*inv, v1.w*inv};
    float4 a2 = {v2.x*inv, v2.y*inv, v2.z*inv, v2.w*inv};
    float4 a3 = {v3.x*inv, v3.y*inv, v3.z*inv, v3.w*inv};
    unsigned int* q = (unsigned int*)(dst + (size_t)r * D_DIM);
    q[lane]       = f2fp8x4(a0);
    q[64 + lane]  = f2fp8x4(a1);
    q[128 + lane] = f2fp8x4(a2);
    q[192 + lane] = f2fp8x4(a3);
}

// 128x128 block tile, BK=128, 4 waves in 2x2; wave owns 64x64 = 2x2 tiles
// of 32x32 via mfma_scale_f32_32x32x64_f8f6f4 (unit e8m0 scales).
//
// CODE-STYLE CONSTRAINT (the R7-R10 spill saga): NO local arrays. R6 (named
// scalars, in-loop pointer increments) allocated 92 VGPR; R7-R10 (pointer /
// offset / f32x16 accumulator ARRAYS indexed in unrolled loops) all pinned
// at 256 VGPR + 57-328 MB scratch — un-promoted locals live in scratch.
// Everything below is a named scalar; the k-loop stays rolled.
//
// LDS row = 128 B = 8 x 16B pieces, XOR swizzle p = (c + row&7) & 7.
__global__ __launch_bounds__(256) void simloss_mxfp8_kernel(
        const unsigned char* __restrict__ Zi8,
        const unsigned char* __restrict__ Zj8,
        float* __restrict__ w, float* __restrict__ out) {
    __shared__ __align__(16) unsigned char lA[128 * 128];  // 16 KB (Zj rows)
    __shared__ __align__(16) unsigned char lB[128 * 128];  // 16 KB (Zi rows)
    __shared__ float rn[4], rp[4];

    const int tid  = threadIdx.x;
    const int lane = tid & 63;
    const int wave = tid >> 6;
    const int wy = wave >> 1, wx = wave & 1;
    const int rowBase = blockIdx.y * 128;   // a (Zj rows)
    const int colBase = blockIdx.x * 128;   // b (Zi rows)

    // --- staging: chunk = 8 rows x 128 B = 1 KB; wave owns chunks 4w..4w+3
    //     of each tile. lane -> row lane>>3, physical piece lane&7.
    const int lrow = lane >> 3;
    const int lp   = lane & 7;
    const int lc   = (lp - lrow) & 7;         // logical piece (swizzle^-1)
    const int ch0  = 4 * wave;
    const unsigned char* pA0 = Zj8 + (size_t)(rowBase + (ch0+0)*8 + lrow) * D_DIM + lc*16;
    const unsigned char* pA1 = Zj8 + (size_t)(rowBase + (ch0+1)*8 + lrow) * D_DIM + lc*16;
    const unsigned char* pA2 = Zj8 + (size_t)(rowBase + (ch0+2)*8 + lrow) * D_DIM + lc*16;
    const unsigned char* pA3 = Zj8 + (size_t)(rowBase + (ch0+3)*8 + lrow) * D_DIM + lc*16;
    const unsigned char* pB0 = Zi8 + (size_t)(colBase + (ch0+0)*8 + lrow) * D_DIM + lc*16;
    const unsigned char* pB1 = Zi8 + (size_t)(colBase + (ch0+1)*8 + lrow) * D_DIM + lc*16;
    const unsigned char* pB2 = Zi8 + (size_t)(colBase + (ch0+2)*8 + lrow) * D_DIM + lc*16;
    const unsigned char* pB3 = Zi8 + (size_t)(colBase + (ch0+3)*8 + lrow) * D_DIM + lc*16;
    unsigned char* sA0 = lA + (ch0+0) * 1024;
    unsigned char* sA1 = lA + (ch0+1) * 1024;
    unsigned char* sA2 = lA + (ch0+2) * 1024;
    unsigned char* sA3 = lA + (ch0+3) * 1024;
    unsigned char* sB0 = lB + (ch0+0) * 1024;
    unsigned char* sB1 = lB + (ch0+1) * 1024;
    unsigned char* sB2 = lB + (ch0+2) * 1024;
    unsigned char* sB3 = lB + (ch0+3) * 1024;

    // --- fragment addressing: lane needs k-bytes kb*64 + h*32 + [0..31]
    //     = logical pieces kb*4 + h*2 + {0,1}; physical p = (c + lane&7) & 7.
    const int r31 = lane & 31;
    const int h   = lane >> 5;
    const int l7  = lane & 7;
    const int o00 = (((0 + 2*h + 0) + l7) & 7) * 16;   // kb=0 first half
    const int o01 = (((0 + 2*h + 1) + l7) & 7) * 16;   // kb=0 second half
    const int o10 = (((4 + 2*h + 0) + l7) & 7) * 16;   // kb=1 first half
    const int o11 = (((4 + 2*h + 1) + l7) & 7) * 16;   // kb=1 second half
    const unsigned char* fA0 = lA + (wy * 64 +  0 + r31) * 128;
    const unsigned char* fA1 = lA + (wy * 64 + 32 + r31) * 128;
    const unsigned char* fB0 = lB + (wx * 64 +  0 + r31) * 128;
    const unsigned char* fB1 = lB + (wx * 64 + 32 + r31) * 128;

    f32x16 acc00 = {0.f}, acc01 = {0.f}, acc10 = {0.f}, acc11 = {0.f};
    #pragma unroll
    for (int r = 0; r < 16; ++r) { acc00[r]=0.f; acc01[r]=0.f; acc10[r]=0.f; acc11[r]=0.f; }

    #pragma unroll 1
    for (int k0 = 0; k0 < D_DIM; k0 += 128) {
        __syncthreads();                    // prior readers done
        gload_lds16(pA0, sA0); gload_lds16(pA1, sA1);
        gload_lds16(pA2, sA2); gload_lds16(pA3, sA3);
        gload_lds16(pB0, sB0); gload_lds16(pB1, sB1);
        gload_lds16(pB2, sB2); gload_lds16(pB3, sB3);
        pA0 += 128; pA1 += 128; pA2 += 128; pA3 += 128;
        pB0 += 128; pB1 += 128; pB2 += 128; pB3 += 128;
        __syncthreads();                    // staging visible

        // kb = 0
        i32x8 a0 = ld_frag(fA0, o00, o01);
        i32x8 a1 = ld_frag(fA1, o00, o01);
        i32x8 b0 = ld_frag(fB0, o00, o01);
        i32x8 b1 = ld_frag(fB1, o00, o01);
        acc00 = __builtin_amdgcn_mfma_scale_f32_32x32x64_f8f6f4(
            a0, b0, acc00, 0, 0, 0, 0x7f7f7f7f, 0, 0x7f7f7f7f);
        acc01 = __builtin_amdgcn_mfma_scale_f32_32x32x64_f8f6f4(
            a0, b1, acc01, 0, 0, 0, 0x7f7f7f7f, 0, 0x7f7f7f7f);
        acc10 = __builtin_amdgcn_mfma_scale_f32_32x32x64_f8f6f4(
            a1, b0, acc10, 0, 0, 0, 0x7f7f7f7f, 0, 0x7f7f7f7f);
        acc11 = __builtin_amdgcn_mfma_scale_f32_32x32x64_f8f6f4(
            a1, b1, acc11, 0, 0, 0, 0x7f7f7f7f, 0, 0x7f7f7f7f);
        // kb = 1 (reuse the same named fragment registers)
        a0 = ld_frag(fA0, o10, o11);
        a1 = ld_frag(fA1, o10, o11);
        b0 = ld_frag(fB0, o10, o11);
        b1 = ld_frag(fB1, o10, o11);
        acc00 = __builtin_amdgcn_mfma_scale_f32_32x32x64_f8f6f4(
            a0, b0, acc00, 0, 0, 0, 0x7f7f7f7f, 0, 0x7f7f7f7f);
        acc01 = __builtin_amdgcn_mfma_scale_f32_32x32x64_f8f6f4(
            a0, b1, acc01, 0, 0, 0, 0x7f7f7f7f, 0, 0x7f7f7f7f);
        acc10 = __builtin_amdgcn_mfma_scale_f32_32x32x64_f8f6f4(
            a1, b0, acc10, 0, 0, 0, 0x7f7f7f7f, 0, 0x7f7f7f7f);
        acc11 = __builtin_amdgcn_mfma_scale_f32_32x32x64_f8f6f4(
            a1, b1, acc11, 0, 0, 0, 0x7f7f7f7f, 0, 0x7f7f7f7f);
    }

    // --- fused epilogue (named accs through the verified C layout)
    const int erow = rowBase + wy * 64 + h * 4;
    const int ecol = colBase + wx * 64 + r31;
    float neg = 0.f, pos = 0.f;
    acc_tile(acc00, erow +  0, ecol +  0, neg, pos);
    acc_tile(acc01, erow +  0, ecol + 32, neg, pos);
    acc_tile(acc10, erow + 32, ecol +  0, neg, pos);
    acc_tile(acc11, erow + 32, ecol + 32, neg, pos);

    #pragma unroll
    for (int o = 32; o > 0; o >>= 1) {
        neg += __shfl_down(neg, o, 64);
        pos += __shfl_down(pos, o, 64);
    }
    if (lane == 0) { rn[wave] = neg; rp[wave] = pos; }
    __syncthreads();
    if (tid == 0) {
        atomicAdd(&w[1], rn[0] + rn[1] + rn[2] + rn[3]);
        if (blockIdx.x == blockIdx.y)       // diagonal tile
            atomicAdd(&w[0], rp[0] + rp[1] + rp[2] + rp[3]);
        __threadfence();
        unsigned int done = atomicAdd(((unsigned int*)w) + 2, 1u);
        if (done == gridDim.x * gridDim.y - 1) {   // last block finalizes
            const float psum = atomicAdd(&w[0], 0.0f);
            const float nsum = atomicAdd(&w[1], 0.0f);
            out[0] = 0.5f * (psum / (float)B_ROWS)
                   + 0.5f * (nsum / ((float)B_ROWS * (float)(B_ROWS - 1)));
        }
    }
}

extern "C" void kernel_launch(void* const* d_in, const int* in_sizes, int n_in,
                              void* d_out, int out_size, void* d_ws, size_t ws_size,
                              hipStream_t stream) {
    const float* emb_i = (const float*)d_in[0];
    const float* emb_j = (const float*)d_in[1];
    float* w = (float*)d_ws;
    unsigned char* Zi8 = (unsigned char*)(w + 16);
    unsigned char* Zj8 = Zi8 + (size_t)B_ROWS * D_DIM;
    float* out = (float*)d_out;

    norm_cast_kernel<<<2 * B_ROWS / 4, 256, 0, stream>>>(emb_i, emb_j, Zi8, Zj8, w);
    dim3 grid(B_ROWS / 128, B_ROWS / 128);   // 32 x 32 = 1024 blocks
    simloss_mxfp8_kernel<<<grid, 256, 0, stream>>>(Zi8, Zj8, w, out);
}